// Round 4
// baseline (3876.568 us; speedup 1.0000x reference)
//
#include <hip/hip_runtime.h>
#include <math.h>
#include <stdint.h>

#define NB 16      // batch
#define TT 24      // time steps
#define VV 8000    // vocab (without blank)
#define VP1 8001
#define DD 1024    // d_model
#define KW 16      // beam width
#define MMAX 256   // NB*KW
#define KSPLIT 4
#define KCHUNK 256 // DD / KSPLIT

typedef unsigned long long u64;
typedef unsigned int u32;

// pack (value desc, index asc) into one u64 so that larger key == better.
// valid only for value >= 0 (all probabilities here are strictly positive).
__device__ __forceinline__ u64 packkey(float v, u32 idx) {
    return ((u64)__float_as_uint(v) << 32) | (u64)(0xFFFFFFFFu - idx);
}

// ---------------------------------------------------------------------------
// GEMM: partial[kc][row][col] = sum_{k in chunk kc} (tok_emb[ptok[row]][k] +
//                                time_emb[t][k]) * W[k][col]
// grid (126, 16): x = 64-col strip, y = (rowblock<<2)|kchunk; BM=64, BN=64.
// 256 threads; per-thread 4 rows x 4 cols; BK=16 double-buffered in LDS.
// 2016 blocks x 4 waves @ <=64 VGPR -> ~8 waves/SIMD: latency hidden by TLP.
// Accumulation order per output is IDENTICAL to all previous passing kernels:
// k ascending within each contiguous 256-k chunk (single fmaf chain).
// ---------------------------------------------------------------------------
__global__ __launch_bounds__(256, 8) void gemm_step(
    const float* __restrict__ tok_emb, const float* __restrict__ tim_emb,
    const float* __restrict__ W, const int* __restrict__ ylast,
    float* __restrict__ partial, int M, int t)
{
    __shared__ float As[2][16][64];
    const int tid = threadIdx.x;
    const int kc = blockIdx.y & 3;
    const int rb = blockIdx.y >> 2;
    if (rb * 64 >= M) return;   // uniform early-out (t==0 upper row-blocks)

    const int tcol = tid & 15;
    const int trow = tid >> 4;
    int c0 = blockIdx.x * 64 + tcol * 4;
    if (c0 > VP1 - 4) c0 = VP1 - 4;   // last block: clamp; duplicate cols get
                                      // bit-identical values -> benign dup stores
    const int r0 = rb * 64 + trow * 4;
    const bool active = (r0 < M);     // skip FMA work for rows beyond M (t==0)
    const int kbase = kc * KCHUNK;

    const int arow = tid & 63;         // staged row within this row-block
    const int kq = (tid >> 6) * 4;     // 0,4,8,12: k-quarter of the 16-k tile
    const int grow = rb * 64 + arow;
    const int ptok = (t == 0) ? VV : ylast[grow];
    const float* __restrict__ ap = tok_emb + (size_t)ptok * DD + kbase + kq;
    const float* __restrict__ tp = tim_emb + (size_t)t * DD + kbase + kq;

    float acc[4][4];
#pragma unroll
    for (int r = 0; r < 4; ++r)
#pragma unroll
        for (int c = 0; c < 4; ++c) acc[r][c] = 0.f;

    // prologue A prefetch
    float4 a0 = *(const float4*)(ap);
    float4 t0 = *(const float4*)(tp);

    const float* __restrict__ wcol = W + (size_t)kbase * VP1 + c0;

    for (int kk = 0; kk < KCHUNK; kk += 16) {
        const int buf = (kk >> 4) & 1;
        {
            float av[4] = { a0.x + t0.x, a0.y + t0.y, a0.z + t0.z, a0.w + t0.w };
#pragma unroll
            for (int q = 0; q < 4; ++q) As[buf][kq + q][arow] = av[q];
        }
        __syncthreads();   // single barrier per tile (double-buffered LDS)
        if (kk + 16 < KCHUNK) {        // prefetch next A tile into registers
            a0 = *(const float4*)(ap + kk + 16);
            t0 = *(const float4*)(tp + kk + 16);
        }
        if (active) {
            const float* __restrict__ wk = wcol + (size_t)kk * VP1;
#pragma unroll
            for (int k2 = 0; k2 < 16; ++k2) {
                const float4 w4 = *(const float4*)(wk);
                const float4 a4 = *(const float4*)(&As[buf][k2][trow * 4]);
                acc[0][0] = fmaf(a4.x, w4.x, acc[0][0]);
                acc[0][1] = fmaf(a4.x, w4.y, acc[0][1]);
                acc[0][2] = fmaf(a4.x, w4.z, acc[0][2]);
                acc[0][3] = fmaf(a4.x, w4.w, acc[0][3]);
                acc[1][0] = fmaf(a4.y, w4.x, acc[1][0]);
                acc[1][1] = fmaf(a4.y, w4.y, acc[1][1]);
                acc[1][2] = fmaf(a4.y, w4.z, acc[1][2]);
                acc[1][3] = fmaf(a4.y, w4.w, acc[1][3]);
                acc[2][0] = fmaf(a4.z, w4.x, acc[2][0]);
                acc[2][1] = fmaf(a4.z, w4.y, acc[2][1]);
                acc[2][2] = fmaf(a4.z, w4.z, acc[2][2]);
                acc[2][3] = fmaf(a4.z, w4.w, acc[2][3]);
                acc[3][0] = fmaf(a4.w, w4.x, acc[3][0]);
                acc[3][1] = fmaf(a4.w, w4.y, acc[3][1]);
                acc[3][2] = fmaf(a4.w, w4.z, acc[3][2]);
                acc[3][3] = fmaf(a4.w, w4.w, acc[3][3]);
                wk += VP1;
            }
        }
    }

    float* __restrict__ outp = partial + (size_t)kc * ((size_t)MMAX * VP1);
#pragma unroll
    for (int r = 0; r < 4; ++r) {
        const int row = r0 + r;
        if (row < M) {
            float* __restrict__ op = outp + (size_t)row * VP1 + c0;
            op[0] = acc[r][0]; op[1] = acc[r][1];
            op[2] = acc[r][2]; op[3] = acc[r][3];
        }
    }
}

// ---------------------------------------------------------------------------
// Per candidate-row: sum split-K partials, softmax, scale by probs_prev,
// apply the precomputed exact-match mask, emit per-row (mx, scale) and the
// EXACT top-16 unmasked ext candidates (wave-local top-16 + cross-wave merge).
// ---------------------------------------------------------------------------
__global__ __launch_bounds__(256) void sm_topk1(
    const float* __restrict__ partial,
    const float* __restrict__ pprev, const int* __restrict__ mtok,
    float* __restrict__ scrv, int* __restrict__ scrc,
    float* __restrict__ rowmx, float* __restrict__ rowsc,
    int Kp)
{
    const int b = blockIdx.x;          // row = n*Kp + i
    const int tid = threadIdx.x;
    const int lane = tid & 63, wid = tid >> 6;
    const int n = b / Kp, i = b % Kp;

    float l[32];
#pragma unroll
    for (int q = 0; q < 32; ++q) {
        int col = q * 256 + tid;
        float s = -INFINITY;
        if (col < VP1) {
            s = 0.f;
            for (int sp = 0; sp < KSPLIT; ++sp)
                s += partial[(size_t)sp * ((size_t)MMAX * VP1) + (size_t)b * VP1 + col];
        }
        l[q] = s;
    }
    // row max
    float mx = -INFINITY;
#pragma unroll
    for (int q = 0; q < 32; ++q) mx = fmaxf(mx, l[q]);
#pragma unroll
    for (int off = 32; off; off >>= 1) mx = fmaxf(mx, __shfl_xor(mx, off));
    __shared__ float redf[4];
    if (lane == 0) redf[wid] = mx;
    __syncthreads();
    mx = fmaxf(fmaxf(redf[0], redf[1]), fmaxf(redf[2], redf[3]));
    // exp + sum
    float sum = 0.f;
#pragma unroll
    for (int q = 0; q < 32; ++q) {
        int col = q * 256 + tid;
        float e = (col < VP1) ? expf(l[q] - mx) : 0.f;
        l[q] = e; sum += e;
    }
#pragma unroll
    for (int off = 32; off; off >>= 1) sum += __shfl_xor(sum, off);
    __shared__ float reds[4];
    __syncthreads();
    if (lane == 0) reds[wid] = sum;
    __syncthreads();
    sum = reds[0] + reds[1] + reds[2] + reds[3];

    const float scale = pprev[n * KW + i] / sum;
    if (tid == 0) { rowmx[b] = mx; rowsc[b] = scale; }
#pragma unroll
    for (int q = 0; q < 32; ++q) {
        int col = q * 256 + tid;
        float p = l[q] * scale;
        l[q] = (col < VV) ? p : -1.0f;   // exclude nonext col + OOB from ext top-k
    }

    // apply the exact-match mask precomputed from the previous state
    {
        const int* __restrict__ mrow = mtok + (n * KW + i) * KW;
#pragma unroll
        for (int j = 0; j < KW; ++j) {
            int tk = mrow[j];
            if (tk >= 0 && (tk & 255) == tid) l[tk >> 8] = -1.0f;
        }
    }

    // wave-local exact top-16 (no block barriers)
    u32 taken = 0;
    float hv = -1.f; int hq = -1;
#pragma unroll
    for (int q = 0; q < 32; ++q)
        if (l[q] > hv) { hv = l[q]; hq = q; }

    __shared__ u64 wtop[4 * 16];
    for (int r = 0; r < 16; ++r) {
        u64 k = (hq < 0) ? 0ull : packkey(hv, (u32)(hq * 256 + tid));
        u64 m = k;
#pragma unroll
        for (int off = 32; off; off >>= 1) {
            u64 o = __shfl_xor(m, off);
            if (o > m) m = o;
        }
        if (lane == 0) wtop[wid * 16 + r] = m;
        if (m && k == m) {
            taken |= (1u << hq);
            hv = -1.f; hq = -1;
#pragma unroll
            for (int q = 0; q < 32; ++q)
                if (!((taken >> q) & 1u) && l[q] > hv) { hv = l[q]; hq = q; }
        }
    }
    __syncthreads();

    // single-wave 64 -> 16 merge
    if (tid < 64) {
        u64 key = wtop[tid];
        for (int r = 0; r < 16; ++r) {
            u64 m = key;
#pragma unroll
            for (int off = 32; off; off >>= 1) {
                u64 o = __shfl_xor(m, off);
                if (o > m) m = o;
            }
            if (tid == 0) {
                scrv[b * 16 + r] = __uint_as_float((u32)(m >> 32));
                scrc[b * 16 + r] = (int)(0xFFFFFFFFu - (u32)m);
            }
            if (m && key == m) key = 0ull;
        }
    }
}

// recompute one scaled prob exactly as sm_topk1 computed it
__device__ __forceinline__ float cand_at(const float* __restrict__ partial,
                                         int b, int col, float mx, float sc) {
    float s = 0.f;
#pragma unroll
    for (int sp = 0; sp < KSPLIT; ++sp)
        s += partial[(size_t)sp * ((size_t)MMAX * VP1) + (size_t)b * VP1 + col];
    return expf(s - mx) * sc;
}

// ---------------------------------------------------------------------------
// Per batch: nonext merge sums, exact top-16 of the pooled candidates
// (rows were pre-masked), the full state update, and the next step's
// exact-match token mask.
// ---------------------------------------------------------------------------
__global__ __launch_bounds__(256) void topk2_update(
    const float* __restrict__ partial,
    const float* __restrict__ rowmx, const float* __restrict__ rowsc,
    const float* __restrict__ scrv, const int* __restrict__ scrc,
    const int* __restrict__ lens_in, const int* __restrict__ cond_in,
    const unsigned char* __restrict__ pref_in,
    float* __restrict__ pprev_out, int* __restrict__ lens_out,
    int* __restrict__ cond_out, unsigned char* __restrict__ pref_out,
    int* __restrict__ ylast, int* __restrict__ mtok, int Kp)
{
    const int n = blockIdx.x, tid = threadIdx.x;
    const int lane = tid & 63, wid = tid >> 6;
    const int i = tid >> 4, j = tid & 15;

    __shared__ int   s_lens[KW];
    __shared__ float s_rmx[KW], s_rsc[KW];
    __shared__ float s_g[KW * KW];
    __shared__ float s_nx[KW];

    if (tid < KW) s_lens[tid] = (tid < Kp) ? lens_in[n * KW + tid] : 0;
    if (tid < Kp) { s_rmx[tid] = rowmx[n * Kp + tid]; s_rsc[tid] = rowsc[n * Kp + tid]; }
    __syncthreads();

    {
        // exact-match gathers for nonext sums; mtok holds this step's tokens
        int tok = mtok[(n * KW + i) * KW + j];
        s_g[i * KW + j] = (tok >= 0)
            ? cand_at(partial, n * Kp + i, tok, s_rmx[i], s_rsc[i]) : 0.f;
    }
    __syncthreads();
    if (tid < Kp) {
        float s = cand_at(partial, n * Kp + tid, VV, s_rmx[tid], s_rsc[tid]);
        for (int ii = 0; ii < Kp; ++ii) s += s_g[ii * KW + tid];
        s_nx[tid] = s;
    }
    __syncthreads();

    // candidate pool: Kp*16 pre-masked ext entries + Kp nonext entries
#define POOLN 272
    __shared__ u64 pool[POOLN];
    for (int e = tid; e < POOLN; e += 256) {
        u64 key = 0ull;
        if (e < Kp * 16) {
            int r = e >> 4, q = e & 15;
            float v = scrv[(n * Kp + r) * 16 + q];
            int col = scrc[(n * Kp + r) * 16 + q];
            key = packkey(v, (u32)(r * VV + col));
        } else if (e >= KW * 16 && e < KW * 16 + Kp) {
            int jj = e - KW * 16;
            key = packkey(s_nx[jj], (u32)(Kp * VV + jj));
        }
        pool[e] = key;
    }
    __syncthreads();

    __shared__ u64 s_top[KW];
    __shared__ u64 redk[4];
    for (int r = 0; r < KW; ++r) {
        u64 k0 = pool[tid];
        u64 k1 = (tid < 16) ? pool[tid + 256] : 0ull;
        u64 m = (k0 > k1) ? k0 : k1;
#pragma unroll
        for (int off = 32; off; off >>= 1) {
            u64 o = __shfl_xor(m, off);
            if (o > m) m = o;
        }
        if (lane == 0) redk[wid] = m;
        __syncthreads();
        m = redk[0];
        if (redk[1] > m) m = redk[1];
        if (redk[2] > m) m = redk[2];
        if (redk[3] > m) m = redk[3];
        if (tid == 0) s_top[r] = m;
        if (m) {
            if (pool[tid] == m)       pool[tid] = 0;
            if (tid < 16 && pool[tid + 256] == m) pool[tid + 256] = 0;
        }
        __syncthreads();
    }

    // decode + state update
    __shared__ int   s_src[KW], s_ext[KW], s_plen[KW], s_lnew[KW], s_nxt[KW];
    __shared__ float s_val[KW];
    if (tid < KW) {
        u64 m = s_top[tid];
        float v = __uint_as_float((u32)(m >> 32));
        int flat = (int)(0xFFFFFFFFu - (u32)m);
        int nx  = (flat >= Kp * VV) ? 1 : 0;
        int src = nx ? (flat - Kp * VV) : (flat / VV);
        int ext = flat % VV;
        s_src[tid] = src; s_ext[tid] = ext; s_nxt[tid] = nx; s_val[tid] = v;
        int pl = s_lens[src];
        s_plen[tid] = pl;
        int ln = pl + (nx ? 0 : 1);
        s_lnew[tid] = ln;
        lens_out[n * KW + tid] = ln;
        ylast[n * KW + tid] = nx ? VV : ext;
    }
    __syncthreads();
    if (tid < KW) pprev_out[n * KW + tid] = s_val[tid] / s_val[0];

    __shared__ int s_cond[TT * KW];
    for (int x = tid; x < TT * KW; x += 256) {
        int k = x & 15;
        s_cond[x] = cond_in[(x >> 4) * (NB * KW) + n * KW + s_src[k]];
    }
    __syncthreads();
    if (tid < KW) s_cond[s_plen[tid] * KW + tid] = s_ext[tid];
    __syncthreads();
    for (int x = tid; x < TT * KW; x += 256)
        cond_out[(x >> 4) * (NB * KW) + n * KW + (x & 15)] = s_cond[x];

    // next prefix matrix + next step's exact-match token mask
    {
        bool p = (pref_in[(n * KW + s_src[i]) * KW + s_src[j]] != 0)
              && (s_lnew[i] <= s_lnew[j]);
        if (p && !s_nxt[i]) {
            int pos = s_lnew[i] - 1; if (pos < 0) pos = 0;
            p = (s_cond[pos * KW + j] == s_ext[i]);
        }
        pref_out[(n * KW + i) * KW + j] = p ? 1 : 0;

        int li = s_lnew[i];
        bool exn = p && (li + 1 == s_lnew[j]);
        int pos2 = (li < TT) ? li : (TT - 1);
        mtok[(n * KW + i) * KW + j] = exn ? s_cond[pos2 * KW + j] : -1;
    }
}

__global__ __launch_bounds__(256) void init_state(
    float* pprev0, int* lens0, int* cond0, unsigned char* pref0, int* mtok)
{
    int idx = blockIdx.x * 256 + threadIdx.x;
    if (idx < TT * NB * KW) cond0[idx] = 0;
    if (idx < NB * KW) { lens0[idx] = 0; pprev0[idx] = 1.0f; }
    if (idx < NB * KW * KW) { pref0[idx] = 1; mtok[idx] = -1; }
}

__global__ __launch_bounds__(256) void finalize_out(
    const int* __restrict__ cond0, const int* __restrict__ lens0,
    const float* __restrict__ pprev0, float* __restrict__ out)
{
    int idx = blockIdx.x * 256 + threadIdx.x;
    const int A = TT * NB * KW, B = NB * KW;
    if (idx < A) out[idx] = (float)cond0[idx];
    else if (idx < A + B) out[idx] = (float)lens0[idx - A];
    else if (idx < A + 2 * B) out[idx] = pprev0[idx - A - B];
}

extern "C" void kernel_launch(void* const* d_in, const int* in_sizes, int n_in,
                              void* d_out, int out_size, void* d_ws, size_t ws_size,
                              hipStream_t stream)
{
    const float* tok = (const float*)d_in[2];   // (V+1, D)
    const float* tim = (const float*)d_in[3];   // (T, D)
    const float* W   = (const float*)d_in[4];   // (D, V+1)

    // workspace layout
    char* ws = (char*)d_ws;
    size_t off = 0;
    auto alloc = [&](size_t bytes) -> void* {
        void* p = ws + off;
        off = (off + bytes + 255) & ~(size_t)255;
        return p;
    };
    const size_t partBytes = (size_t)MMAX * VP1 * sizeof(float);

    float* partial = (float*)alloc((size_t)KSPLIT * partBytes);
    float* scrv    = (float*)alloc((size_t)MMAX * 16 * sizeof(float));
    int*   scrc    = (int*)  alloc((size_t)MMAX * 16 * sizeof(int));
    float* rowmx   = (float*)alloc((size_t)MMAX * sizeof(float));
    float* rowsc   = (float*)alloc((size_t)MMAX * sizeof(float));
    float* pprev[2]; int* lens[2]; int* cond[2]; unsigned char* pref[2];
    for (int p = 0; p < 2; ++p) {
        pprev[p] = (float*)alloc(NB * KW * sizeof(float));
        lens[p]  = (int*)  alloc(NB * KW * sizeof(int));
        cond[p]  = (int*)  alloc((size_t)TT * NB * KW * sizeof(int));
        pref[p]  = (unsigned char*)alloc(NB * KW * KW);
    }
    int* ylast = (int*)alloc(NB * KW * sizeof(int));
    int* mtok  = (int*)alloc((size_t)NB * KW * KW * sizeof(int));

    init_state<<<(TT * NB * KW + 255) / 256, 256, 0, stream>>>(
        pprev[0], lens[0], cond[0], pref[0], mtok);

    for (int t = 0; t < TT; ++t) {
        const int Kp = t ? KW : 1;
        const int M  = NB * Kp;
        const int in = t & 1, out = in ^ 1;
        gemm_step<<<dim3(126, 16), 256, 0, stream>>>(
            tok, tim, W, ylast, partial, M, t);
        sm_topk1<<<M, 256, 0, stream>>>(
            partial, pprev[in], mtok, scrv, scrc, rowmx, rowsc, Kp);
        topk2_update<<<NB, 256, 0, stream>>>(
            partial, rowmx, rowsc, scrv, scrc, lens[in], cond[in], pref[in],
            pprev[out], lens[out], cond[out], pref[out], ylast, mtok, Kp);
    }
    finalize_out<<<(TT * NB * KW + 2 * NB * KW + 255) / 256, 256, 0, stream>>>(
        cond[0], lens[0], pprev[0], (float*)d_out);
}

// Round 6
// 2533.562 us; speedup vs baseline: 1.5301x; 1.5301x over previous
//
#include <hip/hip_runtime.h>
#include <math.h>
#include <stdint.h>

#define NB 16      // batch
#define TT 24      // time steps
#define VV 8000    // vocab (without blank)
#define VP1 8001
#define DD 1024    // d_model
#define KW 16      // beam width
#define MMAX 256   // NB*KW
#define KSPLIT 2
#define KCHUNK 512 // DD / KSPLIT

typedef unsigned long long u64;
typedef unsigned int u32;

// pack (value desc, index asc) into one u64 so that larger key == better.
// valid only for value >= 0 (all probabilities here are strictly positive).
__device__ __forceinline__ u64 packkey(float v, u32 idx) {
    return ((u64)__float_as_uint(v) << 32) | (u64)(0xFFFFFFFFu - idx);
}

// ---------------------------------------------------------------------------
// GEMM: partial[kc][row][col] = sum_{k in chunk kc} (tok_emb[ptok[row]][k] +
//                                time_emb[t][k]) * W[k][col]
// grid (126, 2): x = 64-col strip, y = k-chunk. BM=256 (ALL rows -> W read
// exactly once per step), BN=64. 512 threads, per-thread 8 rows x 4 cols.
// BOTH A and W staged in LDS, double-buffered, ONE barrier per 16-k tile:
// inner loop is pure ds_read_b128 + FMA (no global loads -> no exposed
// L2/HBM latency; LDS latency is compiler-pipelined via lgkmcnt).
// Accumulation: single fmaf chain, k ascending within each 512-k chunk.
// ---------------------------------------------------------------------------
__global__ __launch_bounds__(512, 2) void gemm_step(
    const float* __restrict__ tok_emb, const float* __restrict__ tim_emb,
    const float* __restrict__ W, const int* __restrict__ ylast,
    float* __restrict__ partial, int M, int t)
{
    __shared__ float As[2][16][256];   // 32 KB
    __shared__ float Wt[2][16][64];    //  8 KB
    const int tid = threadIdx.x;
    const int kc = blockIdx.y;
    const int kbase = kc * KCHUNK;

    int cbase = blockIdx.x * 64;
    if (cbase > VP1 - 64) cbase = VP1 - 64;  // last strip: shift left; overlap
                                             // cols recompute identical chains
                                             // -> benign bit-identical dup stores
    const int tcol = tid & 15;
    const int trow = tid >> 4;          // 0..31 -> 8 rows each
    const int c0 = cbase + tcol * 4;
    const int r0 = trow * 8;

    // A staging: thread stages 8 k-values of one row-half
    const int arow  = tid & 255;
    const int khalf = (tid >> 8) * 8;   // 0 or 8
    const int ptok = (t == 0) ? VV : ylast[arow];
    const float* __restrict__ ap = tok_emb + (size_t)ptok * DD + kbase + khalf;
    const float* __restrict__ tp = tim_emb + (size_t)t * DD + kbase + khalf;

    // W staging: thread stages 2 elements (k=wk0 and wk0+8, col wc0)
    const int wk0 = tid >> 6;           // 0..7
    const int wc0 = tid & 63;
    const float* __restrict__ wp = W + (size_t)kbase * VP1 + cbase + wc0;

    float acc[8][4];
#pragma unroll
    for (int r = 0; r < 8; ++r)
#pragma unroll
        for (int c = 0; c < 4; ++c) acc[r][c] = 0.f;

    // prologue: tile 0 into registers
    float4 a0 = *(const float4*)(ap);
    float4 a1 = *(const float4*)(ap + 4);
    float4 t0 = *(const float4*)(tp);
    float4 t1 = *(const float4*)(tp + 4);
    float w0 = wp[(size_t)wk0 * VP1];
    float w1 = wp[(size_t)(wk0 + 8) * VP1];

    for (int kt = 0; kt < KCHUNK; kt += 16) {
        const int buf = (kt >> 4) & 1;
        {
            float av[8] = { a0.x + t0.x, a0.y + t0.y, a0.z + t0.z, a0.w + t0.w,
                            a1.x + t1.x, a1.y + t1.y, a1.z + t1.z, a1.w + t1.w };
#pragma unroll
            for (int q = 0; q < 8; ++q) As[buf][khalf + q][arow] = av[q];
            Wt[buf][wk0][wc0]     = w0;
            Wt[buf][wk0 + 8][wc0] = w1;
        }
        __syncthreads();   // single barrier per tile (double-buffered LDS)
        if (kt + 16 < KCHUNK) {   // prefetch next tile into registers
            a0 = *(const float4*)(ap + kt + 16);
            a1 = *(const float4*)(ap + kt + 20);
            t0 = *(const float4*)(tp + kt + 16);
            t1 = *(const float4*)(tp + kt + 20);
            w0 = wp[(size_t)(kt + 16 + wk0) * VP1];
            w1 = wp[(size_t)(kt + 16 + wk0 + 8) * VP1];
        }
#pragma unroll
        for (int k2 = 0; k2 < 16; ++k2) {
            const float4 wv = *(const float4*)(&Wt[buf][k2][tcol * 4]);
            float a8[8];
            *(float4*)(a8)     = *(const float4*)(&As[buf][k2][r0]);
            *(float4*)(a8 + 4) = *(const float4*)(&As[buf][k2][r0 + 4]);
#pragma unroll
            for (int r = 0; r < 8; ++r) {
                acc[r][0] = fmaf(a8[r], wv.x, acc[r][0]);
                acc[r][1] = fmaf(a8[r], wv.y, acc[r][1]);
                acc[r][2] = fmaf(a8[r], wv.z, acc[r][2]);
                acc[r][3] = fmaf(a8[r], wv.w, acc[r][3]);
            }
        }
    }

    float* __restrict__ outp = partial + (size_t)kc * ((size_t)MMAX * VP1);
#pragma unroll
    for (int r = 0; r < 8; ++r) {
        const int row = r0 + r;
        if (row < M) {
            float* __restrict__ op = outp + (size_t)row * VP1 + c0;
            op[0] = acc[r][0]; op[1] = acc[r][1];
            op[2] = acc[r][2]; op[3] = acc[r][3];
        }
    }
}

// ---------------------------------------------------------------------------
// Per candidate-row: sum split-K partials, softmax, scale by probs_prev,
// apply the precomputed exact-match mask, emit per-row (mx, scale) and the
// EXACT top-16 unmasked ext candidates (wave-local top-16 + cross-wave merge).
// ---------------------------------------------------------------------------
__global__ __launch_bounds__(256) void sm_topk1(
    const float* __restrict__ partial,
    const float* __restrict__ pprev, const int* __restrict__ mtok,
    float* __restrict__ scrv, int* __restrict__ scrc,
    float* __restrict__ rowmx, float* __restrict__ rowsc,
    int Kp)
{
    const int b = blockIdx.x;          // row = n*Kp + i
    const int tid = threadIdx.x;
    const int lane = tid & 63, wid = tid >> 6;
    const int n = b / Kp, i = b % Kp;

    float l[32];
#pragma unroll
    for (int q = 0; q < 32; ++q) {
        int col = q * 256 + tid;
        float s = -INFINITY;
        if (col < VP1) {
            s = 0.f;
            for (int sp = 0; sp < KSPLIT; ++sp)
                s += partial[(size_t)sp * ((size_t)MMAX * VP1) + (size_t)b * VP1 + col];
        }
        l[q] = s;
    }
    // row max
    float mx = -INFINITY;
#pragma unroll
    for (int q = 0; q < 32; ++q) mx = fmaxf(mx, l[q]);
#pragma unroll
    for (int off = 32; off; off >>= 1) mx = fmaxf(mx, __shfl_xor(mx, off));
    __shared__ float redf[4];
    if (lane == 0) redf[wid] = mx;
    __syncthreads();
    mx = fmaxf(fmaxf(redf[0], redf[1]), fmaxf(redf[2], redf[3]));
    // exp + sum
    float sum = 0.f;
#pragma unroll
    for (int q = 0; q < 32; ++q) {
        int col = q * 256 + tid;
        float e = (col < VP1) ? expf(l[q] - mx) : 0.f;
        l[q] = e; sum += e;
    }
#pragma unroll
    for (int off = 32; off; off >>= 1) sum += __shfl_xor(sum, off);
    __shared__ float reds[4];
    __syncthreads();
    if (lane == 0) reds[wid] = sum;
    __syncthreads();
    sum = reds[0] + reds[1] + reds[2] + reds[3];

    const float scale = pprev[n * KW + i] / sum;
    if (tid == 0) { rowmx[b] = mx; rowsc[b] = scale; }
#pragma unroll
    for (int q = 0; q < 32; ++q) {
        int col = q * 256 + tid;
        float p = l[q] * scale;
        l[q] = (col < VV) ? p : -1.0f;   // exclude nonext col + OOB from ext top-k
    }

    // apply the exact-match mask precomputed from the previous state
    {
        const int* __restrict__ mrow = mtok + (n * KW + i) * KW;
#pragma unroll
        for (int j = 0; j < KW; ++j) {
            int tk = mrow[j];
            if (tk >= 0 && (tk & 255) == tid) l[tk >> 8] = -1.0f;
        }
    }

    // wave-local exact top-16 (no block barriers)
    u32 taken = 0;
    float hv = -1.f; int hq = -1;
#pragma unroll
    for (int q = 0; q < 32; ++q)
        if (l[q] > hv) { hv = l[q]; hq = q; }

    __shared__ u64 wtop[4 * 16];
    for (int r = 0; r < 16; ++r) {
        u64 k = (hq < 0) ? 0ull : packkey(hv, (u32)(hq * 256 + tid));
        u64 m = k;
#pragma unroll
        for (int off = 32; off; off >>= 1) {
            u64 o = __shfl_xor(m, off);
            if (o > m) m = o;
        }
        if (lane == 0) wtop[wid * 16 + r] = m;
        if (m && k == m) {
            taken |= (1u << hq);
            hv = -1.f; hq = -1;
#pragma unroll
            for (int q = 0; q < 32; ++q)
                if (!((taken >> q) & 1u) && l[q] > hv) { hv = l[q]; hq = q; }
        }
    }
    __syncthreads();

    // single-wave 64 -> 16 merge
    if (tid < 64) {
        u64 key = wtop[tid];
        for (int r = 0; r < 16; ++r) {
            u64 m = key;
#pragma unroll
            for (int off = 32; off; off >>= 1) {
                u64 o = __shfl_xor(m, off);
                if (o > m) m = o;
            }
            if (tid == 0) {
                scrv[b * 16 + r] = __uint_as_float((u32)(m >> 32));
                scrc[b * 16 + r] = (int)(0xFFFFFFFFu - (u32)m);
            }
            if (m && key == m) key = 0ull;
        }
    }
}

// recompute one scaled prob exactly as sm_topk1 computed it
__device__ __forceinline__ float cand_at(const float* __restrict__ partial,
                                         int b, int col, float mx, float sc) {
    float s = 0.f;
#pragma unroll
    for (int sp = 0; sp < KSPLIT; ++sp)
        s += partial[(size_t)sp * ((size_t)MMAX * VP1) + (size_t)b * VP1 + col];
    return expf(s - mx) * sc;
}

// ---------------------------------------------------------------------------
// Per batch: nonext merge sums, exact top-16 of the pooled candidates
// (rows were pre-masked), the full state update, and the next step's
// exact-match token mask.
// ---------------------------------------------------------------------------
__global__ __launch_bounds__(256) void topk2_update(
    const float* __restrict__ partial,
    const float* __restrict__ rowmx, const float* __restrict__ rowsc,
    const float* __restrict__ scrv, const int* __restrict__ scrc,
    const int* __restrict__ lens_in, const int* __restrict__ cond_in,
    const unsigned char* __restrict__ pref_in,
    float* __restrict__ pprev_out, int* __restrict__ lens_out,
    int* __restrict__ cond_out, unsigned char* __restrict__ pref_out,
    int* __restrict__ ylast, int* __restrict__ mtok, int Kp)
{
    const int n = blockIdx.x, tid = threadIdx.x;
    const int lane = tid & 63, wid = tid >> 6;
    const int i = tid >> 4, j = tid & 15;

    __shared__ int   s_lens[KW];
    __shared__ float s_rmx[KW], s_rsc[KW];
    __shared__ float s_g[KW * KW];
    __shared__ float s_nx[KW];

    if (tid < KW) s_lens[tid] = (tid < Kp) ? lens_in[n * KW + tid] : 0;
    if (tid < Kp) { s_rmx[tid] = rowmx[n * Kp + tid]; s_rsc[tid] = rowsc[n * Kp + tid]; }
    __syncthreads();

    {
        // exact-match gathers for nonext sums; mtok holds this step's tokens
        int tok = mtok[(n * KW + i) * KW + j];
        s_g[i * KW + j] = (tok >= 0)
            ? cand_at(partial, n * Kp + i, tok, s_rmx[i], s_rsc[i]) : 0.f;
    }
    __syncthreads();
    if (tid < Kp) {
        float s = cand_at(partial, n * Kp + tid, VV, s_rmx[tid], s_rsc[tid]);
        for (int ii = 0; ii < Kp; ++ii) s += s_g[ii * KW + tid];
        s_nx[tid] = s;
    }
    __syncthreads();

    // candidate pool: Kp*16 pre-masked ext entries + Kp nonext entries
#define POOLN 272
    __shared__ u64 pool[POOLN];
    for (int e = tid; e < POOLN; e += 256) {
        u64 key = 0ull;
        if (e < Kp * 16) {
            int r = e >> 4, q = e & 15;
            float v = scrv[(n * Kp + r) * 16 + q];
            int col = scrc[(n * Kp + r) * 16 + q];
            key = packkey(v, (u32)(r * VV + col));
        } else if (e >= KW * 16 && e < KW * 16 + Kp) {
            int jj = e - KW * 16;
            key = packkey(s_nx[jj], (u32)(Kp * VV + jj));
        }
        pool[e] = key;
    }
    __syncthreads();

    __shared__ u64 s_top[KW];
    __shared__ u64 redk[4];
    for (int r = 0; r < KW; ++r) {
        u64 k0 = pool[tid];
        u64 k1 = (tid < 16) ? pool[tid + 256] : 0ull;
        u64 m = (k0 > k1) ? k0 : k1;
#pragma unroll
        for (int off = 32; off; off >>= 1) {
            u64 o = __shfl_xor(m, off);
            if (o > m) m = o;
        }
        if (lane == 0) redk[wid] = m;
        __syncthreads();
        m = redk[0];
        if (redk[1] > m) m = redk[1];
        if (redk[2] > m) m = redk[2];
        if (redk[3] > m) m = redk[3];
        if (tid == 0) s_top[r] = m;
        if (m) {
            if (pool[tid] == m)       pool[tid] = 0;
            if (tid < 16 && pool[tid + 256] == m) pool[tid + 256] = 0;
        }
        __syncthreads();
    }

    // decode + state update
    __shared__ int   s_src[KW], s_ext[KW], s_plen[KW], s_lnew[KW], s_nxt[KW];
    __shared__ float s_val[KW];
    if (tid < KW) {
        u64 m = s_top[tid];
        float v = __uint_as_float((u32)(m >> 32));
        int flat = (int)(0xFFFFFFFFu - (u32)m);
        int nx  = (flat >= Kp * VV) ? 1 : 0;
        int src = nx ? (flat - Kp * VV) : (flat / VV);
        int ext = flat % VV;
        s_src[tid] = src; s_ext[tid] = ext; s_nxt[tid] = nx; s_val[tid] = v;
        int pl = s_lens[src];
        s_plen[tid] = pl;
        int ln = pl + (nx ? 0 : 1);
        s_lnew[tid] = ln;
        lens_out[n * KW + tid] = ln;
        ylast[n * KW + tid] = nx ? VV : ext;
    }
    __syncthreads();
    if (tid < KW) pprev_out[n * KW + tid] = s_val[tid] / s_val[0];

    __shared__ int s_cond[TT * KW];
    for (int x = tid; x < TT * KW; x += 256) {
        int k = x & 15;
        s_cond[x] = cond_in[(x >> 4) * (NB * KW) + n * KW + s_src[k]];
    }
    __syncthreads();
    if (tid < KW) s_cond[s_plen[tid] * KW + tid] = s_ext[tid];
    __syncthreads();
    for (int x = tid; x < TT * KW; x += 256)
        cond_out[(x >> 4) * (NB * KW) + n * KW + (x & 15)] = s_cond[x];

    // next prefix matrix + next step's exact-match token mask
    {
        bool p = (pref_in[(n * KW + s_src[i]) * KW + s_src[j]] != 0)
              && (s_lnew[i] <= s_lnew[j]);
        if (p && !s_nxt[i]) {
            int pos = s_lnew[i] - 1; if (pos < 0) pos = 0;
            p = (s_cond[pos * KW + j] == s_ext[i]);
        }
        pref_out[(n * KW + i) * KW + j] = p ? 1 : 0;

        int li = s_lnew[i];
        bool exn = p && (li + 1 == s_lnew[j]);
        int pos2 = (li < TT) ? li : (TT - 1);
        mtok[(n * KW + i) * KW + j] = exn ? s_cond[pos2 * KW + j] : -1;
    }
}

__global__ __launch_bounds__(256) void init_state(
    float* pprev0, int* lens0, int* cond0, unsigned char* pref0, int* mtok)
{
    int idx = blockIdx.x * 256 + threadIdx.x;
    if (idx < TT * NB * KW) cond0[idx] = 0;
    if (idx < NB * KW) { lens0[idx] = 0; pprev0[idx] = 1.0f; }
    if (idx < NB * KW * KW) { pref0[idx] = 1; mtok[idx] = -1; }
}

__global__ __launch_bounds__(256) void finalize_out(
    const int* __restrict__ cond0, const int* __restrict__ lens0,
    const float* __restrict__ pprev0, float* __restrict__ out)
{
    int idx = blockIdx.x * 256 + threadIdx.x;
    const int A = TT * NB * KW, B = NB * KW;
    if (idx < A) out[idx] = (float)cond0[idx];
    else if (idx < A + B) out[idx] = (float)lens0[idx - A];
    else if (idx < A + 2 * B) out[idx] = pprev0[idx - A - B];
}

extern "C" void kernel_launch(void* const* d_in, const int* in_sizes, int n_in,
                              void* d_out, int out_size, void* d_ws, size_t ws_size,
                              hipStream_t stream)
{
    const float* tok = (const float*)d_in[2];   // (V+1, D)
    const float* tim = (const float*)d_in[3];   // (T, D)
    const float* W   = (const float*)d_in[4];   // (D, V+1)

    // workspace layout
    char* ws = (char*)d_ws;
    size_t off = 0;
    auto alloc = [&](size_t bytes) -> void* {
        void* p = ws + off;
        off = (off + bytes + 255) & ~(size_t)255;
        return p;
    };
    const size_t partBytes = (size_t)MMAX * VP1 * sizeof(float);

    float* partial = (float*)alloc((size_t)KSPLIT * partBytes);
    float* scrv    = (float*)alloc((size_t)MMAX * 16 * sizeof(float));
    int*   scrc    = (int*)  alloc((size_t)MMAX * 16 * sizeof(int));
    float* rowmx   = (float*)alloc((size_t)MMAX * sizeof(float));
    float* rowsc   = (float*)alloc((size_t)MMAX * sizeof(float));
    float* pprev[2]; int* lens[2]; int* cond[2]; unsigned char* pref[2];
    for (int p = 0; p < 2; ++p) {
        pprev[p] = (float*)alloc(NB * KW * sizeof(float));
        lens[p]  = (int*)  alloc(NB * KW * sizeof(int));
        cond[p]  = (int*)  alloc((size_t)TT * NB * KW * sizeof(int));
        pref[p]  = (unsigned char*)alloc(NB * KW * KW);
    }
    int* ylast = (int*)alloc(NB * KW * sizeof(int));
    int* mtok  = (int*)alloc((size_t)NB * KW * KW * sizeof(int));

    init_state<<<(TT * NB * KW + 255) / 256, 256, 0, stream>>>(
        pprev[0], lens[0], cond[0], pref[0], mtok);

    for (int t = 0; t < TT; ++t) {
        const int Kp = t ? KW : 1;
        const int M  = NB * Kp;
        const int in = t & 1, out = in ^ 1;
        gemm_step<<<dim3(126, 2), 512, 0, stream>>>(
            tok, tim, W, ylast, partial, M, t);
        sm_topk1<<<M, 256, 0, stream>>>(
            partial, pprev[in], mtok, scrv, scrc, rowmx, rowsc, Kp);
        topk2_update<<<NB, 256, 0, stream>>>(
            partial, rowmx, rowsc, scrv, scrc, lens[in], cond[in], pref[in],
            pprev[out], lens[out], cond[out], pref[out], ylast, mtok, Kp);
    }
    finalize_out<<<(TT * NB * KW + 2 * NB * KW + 255) / 256, 256, 0, stream>>>(
        cond[0], lens[0], pprev[0], (float*)d_out);
}

// Round 7
// 2467.004 us; speedup vs baseline: 1.5714x; 1.0270x over previous
//
#include <hip/hip_runtime.h>
#include <math.h>
#include <stdint.h>

#define NB 16      // batch
#define TT 24      // time steps
#define VV 8000    // vocab (without blank)
#define VP1 8001
#define DD 1024    // d_model
#define KW 16      // beam width
#define MMAX 256   // NB*KW
#define KSPLIT 4
#define KCHUNK 256 // DD / KSPLIT

typedef unsigned long long u64;
typedef unsigned int u32;

// pack (value desc, index asc) into one u64 so that larger key == better.
// valid only for value >= 0 (all probabilities here are strictly positive).
__device__ __forceinline__ u64 packkey(float v, u32 idx) {
    return ((u64)__float_as_uint(v) << 32) | (u64)(0xFFFFFFFFu - idx);
}

// ---------------------------------------------------------------------------
// GEMM: partial[kc][row][col] = sum_{k in chunk kc} (tok_emb[ptok[row]][k] +
//                                time_emb[t][k]) * W[k][col]
// grid (126, 4): x = 64-col strip, y = k-chunk. BM=256 (ALL rows), BN=64.
// 512 threads, per-thread 8 rows x 4 cols. Both A and W staged in LDS,
// double-buffered, ONE barrier per 16-k tile: inner loop is pure
// ds_read_b128 + FMA. KSPLIT=4 -> 504 blocks (~2/CU, 4 waves/SIMD) so
// LDS + staging latency is hidden by TLP (round-6 fix: was 252 blocks,
// 2 waves/SIMD, VALUBusy 44%).
// Accumulation: k ascending within each contiguous 256-k chunk -> partials
// bit-identical to rounds 1-3 (absmax 0.0).
// ---------------------------------------------------------------------------
__global__ __launch_bounds__(512, 2) void gemm_step(
    const float* __restrict__ tok_emb, const float* __restrict__ tim_emb,
    const float* __restrict__ W, const int* __restrict__ ylast,
    float* __restrict__ partial, int M, int t)
{
    __shared__ float As[2][16][256];   // 32 KB
    __shared__ float Wt[2][16][64];    //  8 KB
    const int tid = threadIdx.x;
    const int kc = blockIdx.y;
    const int kbase = kc * KCHUNK;

    int cbase = blockIdx.x * 64;
    if (cbase > VP1 - 64) cbase = VP1 - 64;  // last strip: shift left; overlap
                                             // cols recompute identical chains
                                             // -> benign bit-identical dup stores
    const int tcol = tid & 15;
    const int trow = tid >> 4;          // 0..31 -> 8 rows each
    const int c0 = cbase + tcol * 4;
    const int r0 = trow * 8;

    // A staging: thread stages 8 k-values of one row-half
    const int arow  = tid & 255;
    const int khalf = (tid >> 8) * 8;   // 0 or 8
    const int ptok = (t == 0) ? VV : ylast[arow];
    const float* __restrict__ ap = tok_emb + (size_t)ptok * DD + kbase + khalf;
    const float* __restrict__ tp = tim_emb + (size_t)t * DD + kbase + khalf;

    // W staging: thread stages 2 elements (k=wk0 and wk0+8, col wc0)
    const int wk0 = tid >> 6;           // 0..7
    const int wc0 = tid & 63;
    const float* __restrict__ wp = W + (size_t)kbase * VP1 + cbase + wc0;

    float acc[8][4];
#pragma unroll
    for (int r = 0; r < 8; ++r)
#pragma unroll
        for (int c = 0; c < 4; ++c) acc[r][c] = 0.f;

    // prologue: tile 0 into registers
    float4 a0 = *(const float4*)(ap);
    float4 a1 = *(const float4*)(ap + 4);
    float4 t0 = *(const float4*)(tp);
    float4 t1 = *(const float4*)(tp + 4);
    float w0 = wp[(size_t)wk0 * VP1];
    float w1 = wp[(size_t)(wk0 + 8) * VP1];

    for (int kt = 0; kt < KCHUNK; kt += 16) {
        const int buf = (kt >> 4) & 1;
        {
            float av[8] = { a0.x + t0.x, a0.y + t0.y, a0.z + t0.z, a0.w + t0.w,
                            a1.x + t1.x, a1.y + t1.y, a1.z + t1.z, a1.w + t1.w };
#pragma unroll
            for (int q = 0; q < 8; ++q) As[buf][khalf + q][arow] = av[q];
            Wt[buf][wk0][wc0]     = w0;
            Wt[buf][wk0 + 8][wc0] = w1;
        }
        __syncthreads();   // single barrier per tile (double-buffered LDS)
        if (kt + 16 < KCHUNK) {   // prefetch next tile into registers
            a0 = *(const float4*)(ap + kt + 16);
            a1 = *(const float4*)(ap + kt + 20);
            t0 = *(const float4*)(tp + kt + 16);
            t1 = *(const float4*)(tp + kt + 20);
            w0 = wp[(size_t)(kt + 16 + wk0) * VP1];
            w1 = wp[(size_t)(kt + 16 + wk0 + 8) * VP1];
        }
#pragma unroll
        for (int k2 = 0; k2 < 16; ++k2) {
            const float4 wv = *(const float4*)(&Wt[buf][k2][tcol * 4]);
            float a8[8];
            *(float4*)(a8)     = *(const float4*)(&As[buf][k2][r0]);
            *(float4*)(a8 + 4) = *(const float4*)(&As[buf][k2][r0 + 4]);
#pragma unroll
            for (int r = 0; r < 8; ++r) {
                acc[r][0] = fmaf(a8[r], wv.x, acc[r][0]);
                acc[r][1] = fmaf(a8[r], wv.y, acc[r][1]);
                acc[r][2] = fmaf(a8[r], wv.z, acc[r][2]);
                acc[r][3] = fmaf(a8[r], wv.w, acc[r][3]);
            }
        }
    }

    float* __restrict__ outp = partial + (size_t)kc * ((size_t)MMAX * VP1);
#pragma unroll
    for (int r = 0; r < 8; ++r) {
        const int row = r0 + r;
        if (row < M) {
            float* __restrict__ op = outp + (size_t)row * VP1 + c0;
            op[0] = acc[r][0]; op[1] = acc[r][1];
            op[2] = acc[r][2]; op[3] = acc[r][3];
        }
    }
}

// ---------------------------------------------------------------------------
// Per candidate-row: sum split-K partials, softmax, scale by probs_prev,
// apply the precomputed exact-match mask, emit per-row (mx, scale) and the
// EXACT top-16 unmasked ext candidates (wave-local top-16 + cross-wave merge).
// ---------------------------------------------------------------------------
__global__ __launch_bounds__(256) void sm_topk1(
    const float* __restrict__ partial,
    const float* __restrict__ pprev, const int* __restrict__ mtok,
    float* __restrict__ scrv, int* __restrict__ scrc,
    float* __restrict__ rowmx, float* __restrict__ rowsc,
    int Kp)
{
    const int b = blockIdx.x;          // row = n*Kp + i
    const int tid = threadIdx.x;
    const int lane = tid & 63, wid = tid >> 6;
    const int n = b / Kp, i = b % Kp;

    float l[32];
#pragma unroll
    for (int q = 0; q < 32; ++q) {
        int col = q * 256 + tid;
        float s = -INFINITY;
        if (col < VP1) {
            s = 0.f;
            for (int sp = 0; sp < KSPLIT; ++sp)
                s += partial[(size_t)sp * ((size_t)MMAX * VP1) + (size_t)b * VP1 + col];
        }
        l[q] = s;
    }
    // row max
    float mx = -INFINITY;
#pragma unroll
    for (int q = 0; q < 32; ++q) mx = fmaxf(mx, l[q]);
#pragma unroll
    for (int off = 32; off; off >>= 1) mx = fmaxf(mx, __shfl_xor(mx, off));
    __shared__ float redf[4];
    if (lane == 0) redf[wid] = mx;
    __syncthreads();
    mx = fmaxf(fmaxf(redf[0], redf[1]), fmaxf(redf[2], redf[3]));
    // exp + sum
    float sum = 0.f;
#pragma unroll
    for (int q = 0; q < 32; ++q) {
        int col = q * 256 + tid;
        float e = (col < VP1) ? expf(l[q] - mx) : 0.f;
        l[q] = e; sum += e;
    }
#pragma unroll
    for (int off = 32; off; off >>= 1) sum += __shfl_xor(sum, off);
    __shared__ float reds[4];
    __syncthreads();
    if (lane == 0) reds[wid] = sum;
    __syncthreads();
    sum = reds[0] + reds[1] + reds[2] + reds[3];

    const float scale = pprev[n * KW + i] / sum;
    if (tid == 0) { rowmx[b] = mx; rowsc[b] = scale; }
#pragma unroll
    for (int q = 0; q < 32; ++q) {
        int col = q * 256 + tid;
        float p = l[q] * scale;
        l[q] = (col < VV) ? p : -1.0f;   // exclude nonext col + OOB from ext top-k
    }

    // apply the exact-match mask precomputed from the previous state
    {
        const int* __restrict__ mrow = mtok + (n * KW + i) * KW;
#pragma unroll
        for (int j = 0; j < KW; ++j) {
            int tk = mrow[j];
            if (tk >= 0 && (tk & 255) == tid) l[tk >> 8] = -1.0f;
        }
    }

    // wave-local exact top-16 (no block barriers)
    u32 taken = 0;
    float hv = -1.f; int hq = -1;
#pragma unroll
    for (int q = 0; q < 32; ++q)
        if (l[q] > hv) { hv = l[q]; hq = q; }

    __shared__ u64 wtop[4 * 16];
    for (int r = 0; r < 16; ++r) {
        u64 k = (hq < 0) ? 0ull : packkey(hv, (u32)(hq * 256 + tid));
        u64 m = k;
#pragma unroll
        for (int off = 32; off; off >>= 1) {
            u64 o = __shfl_xor(m, off);
            if (o > m) m = o;
        }
        if (lane == 0) wtop[wid * 16 + r] = m;
        if (m && k == m) {
            taken |= (1u << hq);
            hv = -1.f; hq = -1;
#pragma unroll
            for (int q = 0; q < 32; ++q)
                if (!((taken >> q) & 1u) && l[q] > hv) { hv = l[q]; hq = q; }
        }
    }
    __syncthreads();

    // single-wave 64 -> 16 merge
    if (tid < 64) {
        u64 key = wtop[tid];
        for (int r = 0; r < 16; ++r) {
            u64 m = key;
#pragma unroll
            for (int off = 32; off; off >>= 1) {
                u64 o = __shfl_xor(m, off);
                if (o > m) m = o;
            }
            if (tid == 0) {
                scrv[b * 16 + r] = __uint_as_float((u32)(m >> 32));
                scrc[b * 16 + r] = (int)(0xFFFFFFFFu - (u32)m);
            }
            if (m && key == m) key = 0ull;
        }
    }
}

// recompute one scaled prob exactly as sm_topk1 computed it
__device__ __forceinline__ float cand_at(const float* __restrict__ partial,
                                         int b, int col, float mx, float sc) {
    float s = 0.f;
#pragma unroll
    for (int sp = 0; sp < KSPLIT; ++sp)
        s += partial[(size_t)sp * ((size_t)MMAX * VP1) + (size_t)b * VP1 + col];
    return expf(s - mx) * sc;
}

// ---------------------------------------------------------------------------
// Per batch: nonext merge sums, exact top-16 of the pooled candidates
// (rows were pre-masked), the full state update, and the next step's
// exact-match token mask.
// ---------------------------------------------------------------------------
__global__ __launch_bounds__(256) void topk2_update(
    const float* __restrict__ partial,
    const float* __restrict__ rowmx, const float* __restrict__ rowsc,
    const float* __restrict__ scrv, const int* __restrict__ scrc,
    const int* __restrict__ lens_in, const int* __restrict__ cond_in,
    const unsigned char* __restrict__ pref_in,
    float* __restrict__ pprev_out, int* __restrict__ lens_out,
    int* __restrict__ cond_out, unsigned char* __restrict__ pref_out,
    int* __restrict__ ylast, int* __restrict__ mtok, int Kp)
{
    const int n = blockIdx.x, tid = threadIdx.x;
    const int lane = tid & 63, wid = tid >> 6;
    const int i = tid >> 4, j = tid & 15;

    __shared__ int   s_lens[KW];
    __shared__ float s_rmx[KW], s_rsc[KW];
    __shared__ float s_g[KW * KW];
    __shared__ float s_nx[KW];

    if (tid < KW) s_lens[tid] = (tid < Kp) ? lens_in[n * KW + tid] : 0;
    if (tid < Kp) { s_rmx[tid] = rowmx[n * Kp + tid]; s_rsc[tid] = rowsc[n * Kp + tid]; }
    __syncthreads();

    {
        // exact-match gathers for nonext sums; mtok holds this step's tokens
        int tok = mtok[(n * KW + i) * KW + j];
        s_g[i * KW + j] = (tok >= 0)
            ? cand_at(partial, n * Kp + i, tok, s_rmx[i], s_rsc[i]) : 0.f;
    }
    __syncthreads();
    if (tid < Kp) {
        float s = cand_at(partial, n * Kp + tid, VV, s_rmx[tid], s_rsc[tid]);
        for (int ii = 0; ii < Kp; ++ii) s += s_g[ii * KW + tid];
        s_nx[tid] = s;
    }
    __syncthreads();

    // candidate pool: Kp*16 pre-masked ext entries + Kp nonext entries
#define POOLN 272
    __shared__ u64 pool[POOLN];
    for (int e = tid; e < POOLN; e += 256) {
        u64 key = 0ull;
        if (e < Kp * 16) {
            int r = e >> 4, q = e & 15;
            float v = scrv[(n * Kp + r) * 16 + q];
            int col = scrc[(n * Kp + r) * 16 + q];
            key = packkey(v, (u32)(r * VV + col));
        } else if (e >= KW * 16 && e < KW * 16 + Kp) {
            int jj = e - KW * 16;
            key = packkey(s_nx[jj], (u32)(Kp * VV + jj));
        }
        pool[e] = key;
    }
    __syncthreads();

    __shared__ u64 s_top[KW];
    __shared__ u64 redk[4];
    for (int r = 0; r < KW; ++r) {
        u64 k0 = pool[tid];
        u64 k1 = (tid < 16) ? pool[tid + 256] : 0ull;
        u64 m = (k0 > k1) ? k0 : k1;
#pragma unroll
        for (int off = 32; off; off >>= 1) {
            u64 o = __shfl_xor(m, off);
            if (o > m) m = o;
        }
        if (lane == 0) redk[wid] = m;
        __syncthreads();
        m = redk[0];
        if (redk[1] > m) m = redk[1];
        if (redk[2] > m) m = redk[2];
        if (redk[3] > m) m = redk[3];
        if (tid == 0) s_top[r] = m;
        if (m) {
            if (pool[tid] == m)       pool[tid] = 0;
            if (tid < 16 && pool[tid + 256] == m) pool[tid + 256] = 0;
        }
        __syncthreads();
    }

    // decode + state update
    __shared__ int   s_src[KW], s_ext[KW], s_plen[KW], s_lnew[KW], s_nxt[KW];
    __shared__ float s_val[KW];
    if (tid < KW) {
        u64 m = s_top[tid];
        float v = __uint_as_float((u32)(m >> 32));
        int flat = (int)(0xFFFFFFFFu - (u32)m);
        int nx  = (flat >= Kp * VV) ? 1 : 0;
        int src = nx ? (flat - Kp * VV) : (flat / VV);
        int ext = flat % VV;
        s_src[tid] = src; s_ext[tid] = ext; s_nxt[tid] = nx; s_val[tid] = v;
        int pl = s_lens[src];
        s_plen[tid] = pl;
        int ln = pl + (nx ? 0 : 1);
        s_lnew[tid] = ln;
        lens_out[n * KW + tid] = ln;
        ylast[n * KW + tid] = nx ? VV : ext;
    }
    __syncthreads();
    if (tid < KW) pprev_out[n * KW + tid] = s_val[tid] / s_val[0];

    __shared__ int s_cond[TT * KW];
    for (int x = tid; x < TT * KW; x += 256) {
        int k = x & 15;
        s_cond[x] = cond_in[(x >> 4) * (NB * KW) + n * KW + s_src[k]];
    }
    __syncthreads();
    if (tid < KW) s_cond[s_plen[tid] * KW + tid] = s_ext[tid];
    __syncthreads();
    for (int x = tid; x < TT * KW; x += 256)
        cond_out[(x >> 4) * (NB * KW) + n * KW + (x & 15)] = s_cond[x];

    // next prefix matrix + next step's exact-match token mask
    {
        bool p = (pref_in[(n * KW + s_src[i]) * KW + s_src[j]] != 0)
              && (s_lnew[i] <= s_lnew[j]);
        if (p && !s_nxt[i]) {
            int pos = s_lnew[i] - 1; if (pos < 0) pos = 0;
            p = (s_cond[pos * KW + j] == s_ext[i]);
        }
        pref_out[(n * KW + i) * KW + j] = p ? 1 : 0;

        int li = s_lnew[i];
        bool exn = p && (li + 1 == s_lnew[j]);
        int pos2 = (li < TT) ? li : (TT - 1);
        mtok[(n * KW + i) * KW + j] = exn ? s_cond[pos2 * KW + j] : -1;
    }
}

__global__ __launch_bounds__(256) void init_state(
    float* pprev0, int* lens0, int* cond0, unsigned char* pref0, int* mtok)
{
    int idx = blockIdx.x * 256 + threadIdx.x;
    if (idx < TT * NB * KW) cond0[idx] = 0;
    if (idx < NB * KW) { lens0[idx] = 0; pprev0[idx] = 1.0f; }
    if (idx < NB * KW * KW) { pref0[idx] = 1; mtok[idx] = -1; }
}

__global__ __launch_bounds__(256) void finalize_out(
    const int* __restrict__ cond0, const int* __restrict__ lens0,
    const float* __restrict__ pprev0, float* __restrict__ out)
{
    int idx = blockIdx.x * 256 + threadIdx.x;
    const int A = TT * NB * KW, B = NB * KW;
    if (idx < A) out[idx] = (float)cond0[idx];
    else if (idx < A + B) out[idx] = (float)lens0[idx - A];
    else if (idx < A + 2 * B) out[idx] = pprev0[idx - A - B];
}

extern "C" void kernel_launch(void* const* d_in, const int* in_sizes, int n_in,
                              void* d_out, int out_size, void* d_ws, size_t ws_size,
                              hipStream_t stream)
{
    const float* tok = (const float*)d_in[2];   // (V+1, D)
    const float* tim = (const float*)d_in[3];   // (T, D)
    const float* W   = (const float*)d_in[4];   // (D, V+1)

    // workspace layout
    char* ws = (char*)d_ws;
    size_t off = 0;
    auto alloc = [&](size_t bytes) -> void* {
        void* p = ws + off;
        off = (off + bytes + 255) & ~(size_t)255;
        return p;
    };
    const size_t partBytes = (size_t)MMAX * VP1 * sizeof(float);

    float* partial = (float*)alloc((size_t)KSPLIT * partBytes);
    float* scrv    = (float*)alloc((size_t)MMAX * 16 * sizeof(float));
    int*   scrc    = (int*)  alloc((size_t)MMAX * 16 * sizeof(int));
    float* rowmx   = (float*)alloc((size_t)MMAX * sizeof(float));
    float* rowsc   = (float*)alloc((size_t)MMAX * sizeof(float));
    float* pprev[2]; int* lens[2]; int* cond[2]; unsigned char* pref[2];
    for (int p = 0; p < 2; ++p) {
        pprev[p] = (float*)alloc(NB * KW * sizeof(float));
        lens[p]  = (int*)  alloc(NB * KW * sizeof(int));
        cond[p]  = (int*)  alloc((size_t)TT * NB * KW * sizeof(int));
        pref[p]  = (unsigned char*)alloc(NB * KW * KW);
    }
    int* ylast = (int*)alloc(NB * KW * sizeof(int));
    int* mtok  = (int*)alloc((size_t)NB * KW * KW * sizeof(int));

    init_state<<<(TT * NB * KW + 255) / 256, 256, 0, stream>>>(
        pprev[0], lens[0], cond[0], pref[0], mtok);

    for (int t = 0; t < TT; ++t) {
        const int Kp = t ? KW : 1;
        const int M  = NB * Kp;
        const int in = t & 1, out = in ^ 1;
        gemm_step<<<dim3(126, KSPLIT), 512, 0, stream>>>(
            tok, tim, W, ylast, partial, M, t);
        sm_topk1<<<M, 256, 0, stream>>>(
            partial, pprev[in], mtok, scrv, scrc, rowmx, rowsc, Kp);
        topk2_update<<<NB, 256, 0, stream>>>(
            partial, rowmx, rowsc, scrv, scrc, lens[in], cond[in], pref[in],
            pprev[out], lens[out], cond[out], pref[out], ylast, mtok, Kp);
    }
    finalize_out<<<(TT * NB * KW + 2 * NB * KW + 255) / 256, 256, 0, stream>>>(
        cond[0], lens[0], pprev[0], (float*)d_out);
}